// Round 5
// baseline (74.532 us; speedup 1.0000x reference)
//
#include <hip/hip_runtime.h>

#define E_EDGES 8192
#define KN 32
#define DD 128
#define HH 64
#define XSTR (DD + 8)   // ushort row stride: 272 B

typedef __attribute__((ext_vector_type(8))) __bf16 bf16x8;
typedef __attribute__((ext_vector_type(4))) __bf16 bf16x4;
typedef __attribute__((ext_vector_type(4))) float f32x4;
typedef __attribute__((ext_vector_type(2))) float f32x2;

__device__ __forceinline__ float bf2f(unsigned int u) {
    return __builtin_bit_cast(float, u << 16);
}

// Non-temporal 16B load: W1 is read exactly once per replay (268 MB, larger
// than the 256 MB L3). Without nt it cycles the whole L3 every replay and
// evicts X (51 MB), turning the X gather into HBM misses. nt protects X.
__device__ __forceinline__ f32x4 ntload4(const float* p) {
    return __builtin_nontemporal_load(reinterpret_cast<const f32x4*>(p));
}
__device__ __forceinline__ float ntload1(const float* p) {
    return __builtin_nontemporal_load(p);
}

// Wave-local LDS ordering fence: no s_barrier (waves are independent).
__device__ __forceinline__ void wave_sync_lds() {
    asm volatile("s_waitcnt lgkmcnt(0)" ::: "memory");
    __builtin_amdgcn_wave_barrier();
}

__global__ __launch_bounds__(256, 4)
void he_attn_kernel(const float* __restrict__ X,
                    const int* __restrict__ idx,
                    const float* __restrict__ W1,
                    const float* __restrict__ b1,
                    const float* __restrict__ W2,
                    const float* __restrict__ b2,
                    float* __restrict__ Zout,
                    float* __restrict__ Bout)
{
    const int tid  = threadIdx.x;
    const int lane = tid & 63;
    const int wv   = tid >> 6;              // wave 0..3 — each owns ONE edge
    const int e    = blockIdx.x * 4 + wv;
    const int cl   = lane & 15;             // MFMA col within 16-tile
    const int kg   = lane >> 4;             // MFMA k-chunk group 0..3

    __shared__ __align__(16) unsigned short xsb[4][KN][XSTR];  // per-wave x_he bf16
    __shared__ __align__(16) float ws[4][KN];                  // per-wave w / beta

    // ---- small per-edge params (single-use streams -> nt) ----
    const int iv = idx[(size_t)e * KN + (lane & 31)];
    float b1v[4], w2v[4];
    #pragma unroll
    for (int jt = 0; jt < 4; ++jt) {
        b1v[jt] = ntload1(&b1[(size_t)e * HH + jt * 16 + cl]);
        w2v[jt] = ntload1(&W2[(size_t)e * HH + jt * 16 + cl]);
    }
    const float b2v = ntload1(&b2[e]);

    // ---- W1 N-tile 0 prefetch (nt stream) ----
    const float* W1e = W1 + (size_t)e * HH * DD;
    f32x4 wf[8];
    #pragma unroll
    for (int q = 0; q < 8; ++q)
        wf[q] = ntload4(W1e + (size_t)cl * DD + (q >> 1) * 32 + kg * 8 + (q & 1) * 4);

    // ---- X gather (CACHEABLE - X is the reused, L3-resident operand) ----
    const int rb = lane >> 5;               // 0/1
    const int cc = lane & 31;               // float4 col
    #pragma unroll
    for (int hb = 0; hb < 2; ++hb) {
        float4 xr[8];
        #pragma unroll
        for (int q = 0; q < 8; ++q) {
            int row = __shfl(iv, rb + 2 * (hb * 8 + q));
            xr[q] = reinterpret_cast<const float4*>(X)[(size_t)row * (DD / 4) + cc];
        }
        #pragma unroll
        for (int q = 0; q < 8; ++q) {
            bf16x4 bv;
            bv[0] = (__bf16)xr[q].x; bv[1] = (__bf16)xr[q].y;
            bv[2] = (__bf16)xr[q].z; bv[3] = (__bf16)xr[q].w;
            *reinterpret_cast<bf16x4*>(&xsb[wv][rb + 2 * (hb * 8 + q)][cc * 4]) = bv;
        }
    }
    wave_sync_lds();

    // ---- A fragments: 8 x ds_read_b128, kept in regs for all 4 N-tiles ----
    bf16x8 a0[4], a1[4];
    #pragma unroll
    for (int kc = 0; kc < 4; ++kc) {
        a0[kc] = *reinterpret_cast<const bf16x8*>(&xsb[wv][cl][kc * 32 + kg * 8]);
        a1[kc] = *reinterpret_cast<const bf16x8*>(&xsb[wv][16 + cl][kc * 32 + kg * 8]);
    }

    // ---- N-tile loop: cvt W1 -> bb, prefetch next tile (nt), 8 MFMA, epi ----
    float pk[8] = {0.f,0.f,0.f,0.f,0.f,0.f,0.f,0.f};
    #pragma unroll
    for (int jt = 0; jt < 4; ++jt) {
        bf16x8 bb[4];
        #pragma unroll
        for (int kc = 0; kc < 4; ++kc) {
            f32x4 a = wf[2 * kc], b = wf[2 * kc + 1];
            bf16x8 v;
            v[0] = (__bf16)a[0]; v[1] = (__bf16)a[1]; v[2] = (__bf16)a[2]; v[3] = (__bf16)a[3];
            v[4] = (__bf16)b[0]; v[5] = (__bf16)b[1]; v[6] = (__bf16)b[2]; v[7] = (__bf16)b[3];
            bb[kc] = v;
        }
        if (jt < 3) {
            const float* W1r = W1e + (size_t)((jt + 1) * 16 + cl) * DD;
            #pragma unroll
            for (int q = 0; q < 8; ++q)
                wf[q] = ntload4(W1r + (q >> 1) * 32 + kg * 8 + (q & 1) * 4);
        }
        f32x4 acc0 = {0.f,0.f,0.f,0.f}, acc1 = {0.f,0.f,0.f,0.f};
        #pragma unroll
        for (int kc = 0; kc < 4; ++kc) {
            acc0 = __builtin_amdgcn_mfma_f32_16x16x32_bf16(a0[kc], bb[kc], acc0, 0, 0, 0);
            acc1 = __builtin_amdgcn_mfma_f32_16x16x32_bf16(a1[kc], bb[kc], acc1, 0, 0, 0);
        }
        // h = leaky(acc + b1[j]); fold h * W2[j] into per-lane k-partials
        #pragma unroll
        for (int r = 0; r < 4; ++r) {
            float h0 = acc0[r] + b1v[jt]; h0 = (h0 > 0.f) ? h0 : 0.01f * h0;
            float h1 = acc1[r] + b1v[jt]; h1 = (h1 > 0.f) ? h1 : 0.01f * h1;
            pk[r]     += h0 * w2v[jt];
            pk[4 + r] += h1 * w2v[jt];
        }
    }
    // reduce over the 16 cl-lanes (j's); kg bits untouched by xor<16
    #pragma unroll
    for (int m = 1; m < 16; m <<= 1) {
        #pragma unroll
        for (int q = 0; q < 8; ++q) pk[q] += __shfl_xor(pk[q], m);
    }
    if (cl == 0) {
        #pragma unroll
        for (int r = 0; r < 4; ++r) {
            ws[wv][kg * 4 + r]      = pk[r];       // k rows 0..15
            ws[wv][16 + kg * 4 + r] = pk[4 + r];   // k rows 16..31
        }
    }
    wave_sync_lds();

    // ---- softmax over K=32 (all 64 lanes, halves duplicate) ----
    {
        const int k = lane & 31;
        float v = ws[wv][k] + b2v;
        float mx = v;
        #pragma unroll
        for (int off = 16; off >= 1; off >>= 1) mx = fmaxf(mx, __shfl_xor(mx, off));
        float ex = __expf(v - mx);
        float s = ex;
        #pragma unroll
        for (int off = 16; off >= 1; off >>= 1) s += __shfl_xor(s, off);
        float beta = ex / s;
        if (lane < 32) {
            ws[wv][k] = beta;                       // program-order after the read
            __builtin_nontemporal_store(beta, &Bout[(size_t)e * KN + k]);
        }
    }
    wave_sync_lds();

    // ---- z[d] = sum_k beta[k] x[k][d]; each lane owns d = 2*lane, 2*lane+1 ----
    float z0 = 0.f, z1 = 0.f;
    #pragma unroll
    for (int kq = 0; kq < 8; ++kq) {
        f32x4 bq = *reinterpret_cast<const f32x4*>(&ws[wv][kq * 4]);   // broadcast
        #pragma unroll
        for (int r = 0; r < 4; ++r) {
            unsigned int pr = *reinterpret_cast<const unsigned int*>(
                &xsb[wv][kq * 4 + r][2 * lane]);
            z0 += bq[r] * bf2f(pr & 0xffffu);
            z1 += bq[r] * bf2f(pr >> 16);
        }
    }
    z0 = (z0 > 0.f) ? z0 : 0.01f * z0;
    z1 = (z1 > 0.f) ? z1 : 0.01f * z1;
    f32x2 outv;
    outv[0] = tanhf(z0);
    outv[1] = tanhf(z1);
    __builtin_nontemporal_store(outv,
        reinterpret_cast<f32x2*>(&Zout[(size_t)e * DD + 2 * lane]));
}

extern "C" void kernel_launch(void* const* d_in, const int* in_sizes, int n_in,
                              void* d_out, int out_size, void* d_ws, size_t ws_size,
                              hipStream_t stream) {
    const float* X   = (const float*)d_in[0];
    const int*   idx = (const int*)d_in[1];
    const float* W1  = (const float*)d_in[2];
    const float* b1  = (const float*)d_in[3];
    const float* W2  = (const float*)d_in[4];
    const float* b2  = (const float*)d_in[5];
    float* Zout = (float*)d_out;                       // [E, D]
    float* Bout = Zout + (size_t)E_EDGES * DD;         // [E, K]
    (void)in_sizes; (void)n_in; (void)out_size; (void)d_ws; (void)ws_size;
    he_attn_kernel<<<dim3(E_EDGES / 4), dim3(256), 0, stream>>>(X, idx, W1, b1, W2, b2, Zout, Bout);
}

// Round 6
// 64.640 us; speedup vs baseline: 1.1530x; 1.1530x over previous
//
#include <hip/hip_runtime.h>

#define E_EDGES 8192
#define KN 32
#define DD 128
#define HH 64
#define XPAD 8   // bf16 row padding: row stride 272 B

typedef __attribute__((ext_vector_type(8))) __bf16 bf16x8;
typedef __attribute__((ext_vector_type(8))) unsigned short u16x8;
typedef __attribute__((ext_vector_type(4))) float f32x4;

__device__ __forceinline__ unsigned short f2bf(float f) {
    unsigned int u = __builtin_bit_cast(unsigned int, f);
    u += 0x7FFFu + ((u >> 16) & 1u);   // round-to-nearest-even
    return (unsigned short)(u >> 16);
}

__device__ __forceinline__ bf16x8 pack_bf8(float4 a, float4 b) {
    u16x8 u;
    u[0] = f2bf(a.x); u[1] = f2bf(a.y); u[2] = f2bf(a.z); u[3] = f2bf(a.w);
    u[4] = f2bf(b.x); u[5] = f2bf(b.y); u[6] = f2bf(b.z); u[7] = f2bf(b.w);
    return __builtin_bit_cast(bf16x8, u);
}

__global__ __launch_bounds__(256, 4)
void he_attn_kernel(const float* __restrict__ X,
                    const int* __restrict__ idx,
                    const float* __restrict__ W1,
                    const float* __restrict__ b1,
                    const float* __restrict__ W2,
                    const float* __restrict__ b2,
                    float* __restrict__ Zout,
                    float* __restrict__ Bout)
{
    const int e    = blockIdx.x;
    const int tid  = threadIdx.x;
    const int lane = tid & 63;
    const int wv   = tid >> 6;       // wave 0..3
    const int cl   = lane & 15;      // column within 16-wide tile
    const int kg   = lane >> 4;      // k-chunk group 0..3

    __shared__ unsigned short xsb[KN][DD + XPAD];  // 8.5 KB bf16 x_he
    __shared__ float wpart[4][KN];                 // per-wave partial w[k]
    __shared__ float beta_s[KN];

    // ---- W1 B-fragments: DIRECT global->reg (each row read exactly once,
    //      no reuse -> LDS staging would be pure overhead). Issue all 8
    //      float4 loads up front so they overlap the x-gather below. ----
    const int j = wv * 16 + cl;                    // W1 row this lane feeds
    const float* W1r = W1 + ((size_t)e * HH + j) * DD;
    float4 wf[8];
    #pragma unroll
    for (int kc = 0; kc < 4; ++kc) {
        wf[2 * kc]     = *reinterpret_cast<const float4*>(W1r + kc * 32 + kg * 8);
        wf[2 * kc + 1] = *reinterpret_cast<const float4*>(W1r + kc * 32 + kg * 8 + 4);
    }

    // ---- stage x_he (gather 32 rows x 128 f32) as bf16 into LDS ----
    #pragma unroll
    for (int it = 0; it < 4; ++it) {
        int i = tid + it * 256;
        int k = i >> 5;          // 32 float4-chunks per row
        int c = i & 31;
        int row = idx[e * KN + k];
        float4 v = reinterpret_cast<const float4*>(X)[(size_t)row * (DD / 4) + c];
        ushort4 bv;
        bv.x = f2bf(v.x); bv.y = f2bf(v.y); bv.z = f2bf(v.z); bv.w = f2bf(v.w);
        *reinterpret_cast<ushort4*>(&xsb[k][c * 4]) = bv;
    }
    __syncthreads();

    // ---- h-GEMM: h[32x64] = x_he[32x128] . W1[e]^T, bf16 MFMA, f32 accum ----
    f32x4 acc0 = {0.f, 0.f, 0.f, 0.f};
    f32x4 acc1 = {0.f, 0.f, 0.f, 0.f};
    #pragma unroll
    for (int kc = 0; kc < 4; ++kc) {
        const int ds = kc * 32 + kg * 8;
        bf16x8 a0 = *reinterpret_cast<const bf16x8*>(&xsb[cl][ds]);        // A rows 0..15
        bf16x8 a1 = *reinterpret_cast<const bf16x8*>(&xsb[16 + cl][ds]);   // A rows 16..31
        bf16x8 bb = pack_bf8(wf[2 * kc], wf[2 * kc + 1]);                  // B from regs
        acc0 = __builtin_amdgcn_mfma_f32_16x16x32_bf16(a0, bb, acc0, 0, 0, 0);
        acc1 = __builtin_amdgcn_mfma_f32_16x16x32_bf16(a1, bb, acc1, 0, 0, 0);
    }

    // ---- epilogue: h = leaky(acc + b1[j]); partial w[k] += h * W2[j] ----
    // D layout: col j = wv*16 + (lane&15), row k = mt*16 + (lane>>4)*4 + reg   [m89]
    const float b1j = b1[e * HH + j];
    const float w2j = W2[e * HH + j];
    float pk[8];
    #pragma unroll
    for (int r = 0; r < 4; ++r) {
        float h0 = acc0[r] + b1j; h0 = (h0 > 0.f) ? h0 : 0.01f * h0;
        float h1 = acc1[r] + b1j; h1 = (h1 > 0.f) ? h1 : 0.01f * h1;
        pk[r]     = h0 * w2j;
        pk[4 + r] = h1 * w2j;
    }
    // reduce over the 16 lanes sharing (lane>>4)  (the 16 j's of this wave)
    #pragma unroll
    for (int m = 1; m < 16; m <<= 1) {
        #pragma unroll
        for (int q = 0; q < 8; ++q) pk[q] += __shfl_xor(pk[q], m);
    }
    if (cl == 0) {
        #pragma unroll
        for (int r = 0; r < 4; ++r) {
            wpart[wv][kg * 4 + r]      = pk[r];
            wpart[wv][16 + kg * 4 + r] = pk[4 + r];
        }
    }
    __syncthreads();

    // ---- softmax over K=32 (lanes 0..31 of wave 0) ----
    if (tid < KN) {
        float v = b2[e] + wpart[0][tid] + wpart[1][tid] + wpart[2][tid] + wpart[3][tid];
        float mx = v;
        #pragma unroll
        for (int off = 16; off >= 1; off >>= 1) mx = fmaxf(mx, __shfl_xor(mx, off));
        float ex = __expf(v - mx);
        float s = ex;
        #pragma unroll
        for (int off = 16; off >= 1; off >>= 1) s += __shfl_xor(s, off);
        float beta = ex / s;
        beta_s[tid] = beta;
        Bout[(size_t)e * KN + tid] = beta;
    }
    __syncthreads();

    // ---- z[d] = sum_k beta[k] * x_he[k][d] (bf16 x, exact f32 accum),
    //      Z = tanh(leaky(z)) ----
    if (tid < DD) {
        float z = 0.f;
        #pragma unroll
        for (int k = 0; k < KN; ++k) {
            unsigned int b = xsb[k][tid];
            float xv = __builtin_bit_cast(float, b << 16);   // bf16->f32 exact
            z += beta_s[k] * xv;
        }
        z = (z > 0.f) ? z : 0.01f * z;
        Zout[(size_t)e * DD + tid] = tanhf(z);
    }
}

extern "C" void kernel_launch(void* const* d_in, const int* in_sizes, int n_in,
                              void* d_out, int out_size, void* d_ws, size_t ws_size,
                              hipStream_t stream) {
    const float* X   = (const float*)d_in[0];
    const int*   idx = (const int*)d_in[1];
    const float* W1  = (const float*)d_in[2];
    const float* b1  = (const float*)d_in[3];
    const float* W2  = (const float*)d_in[4];
    const float* b2  = (const float*)d_in[5];
    float* Zout = (float*)d_out;                       // [E, D]
    float* Bout = Zout + (size_t)E_EDGES * DD;         // [E, K]
    (void)in_sizes; (void)n_in; (void)out_size; (void)d_ws; (void)ws_size;
    he_attn_kernel<<<dim3(E_EDGES), dim3(256), 0, stream>>>(X, idx, W1, b1, W2, b2, Zout, Bout);
}